// Round 5
// baseline (194.747 us; speedup 1.0000x reference)
//
#include <hip/hip_runtime.h>
#include <math.h>

// CMCV3Loss: B=512, S=8, D=128, H=64. Inputs: 4 x (4096x128 fp32), seq_len.
// bf16-MFMA symmetric grams; loss_row = lse_{m!=n} - pos. Fixed max-shift:
// ex = exp((s-1)*INV_T) = exp2(fma(s, C1EXP, -C1EXP)) since s<=1 for normalized vecs.
// 2 launches: k_prep (norms+bf16 convert+small dots+zeroing), k_gram (+fused tail).
// Tail sync: RELAXED arrival counter (ACQ_REL regressed 2.2x in R4 — per-block
// agent-scope fences emit L2 wb/inv, serialized across 3456 blocks). Correctness:
// __syncthreads drains vmcnt(0) => rowsum atomics completed at the device coherent
// point before the counter RMW issues; tail reads rowsums with relaxed agent-scope
// atomic loads (bypass stale L1/L2).
//
// ws float offsets:
#define RS_T   49152    // temporal rowsums [4][4096]
#define RS_C   65536    // contrastive rowsums [4 calls][8 p][1024]
#define SLOT   98304    // slots stride 32: 16..23 ortho, 24 posC, 25 posT, 26 arrival ctr
// ws byte offsets (bf16 arrays):
#define ZF_BYTE 397312   // znfull bf16 [4][4096][128]
#define ZH_BYTE 4591616  // znhalf bf16 [4][4096][128] (cols 0..63 sh-normed, 64..127 pv-normed)

#define INV_T 14.285714285714286f
#define C1EXP 20.609929155556627f   // INV_T * log2(e)
#define EPS_N 1e-8f
#define NBLK_GRAM 3456

typedef __attribute__((ext_vector_type(8))) short short8;
typedef __attribute__((ext_vector_type(4))) float floatx4;

__device__ __forceinline__ const float* pick4(const float* a, const float* b,
                                              const float* c, const float* d, int i) {
    return i == 0 ? a : i == 1 ? b : i == 2 ? c : d;
}

__device__ __forceinline__ unsigned short f2bf(float x) {
    unsigned u = __float_as_uint(x);
    u += 0x7fff + ((u >> 16) & 1);
    return (unsigned short)(u >> 16);
}

// ---------- prep: zero RS region, per-sequence norms, bf16 convert, ortho/pos dots ----------
// grid 512 (one per sequence), block 256.
__global__ __launch_bounds__(256) void k_prep(const float* __restrict__ in0, const float* __restrict__ in1,
                                              const float* __restrict__ in2, const float* __restrict__ in3,
                                              float* __restrict__ ws) {
    __shared__ float buf[4][8][128];    // 4 inputs x 8 rows of this sequence
    __shared__ float iv[3][32];         // [sh,pv,full] inverse norms, idx = input*8+row
    __shared__ float red[3];
    const int s = blockIdx.x;
    const int tid = threadIdx.x;

    int gid = s * 256 + tid;            // zero rowsums + slots (49152..99328)
    if (gid < 50176) ws[RS_T + gid] = 0.0f;
    if (tid < 3) red[tid] = 0.0f;

    #pragma unroll
    for (int i = 0; i < 4; i++) {
        int e4 = tid + i * 256;
        int inp = e4 >> 8, row = (e4 >> 5) & 7, c4 = e4 & 31;
        float4 f = *(const float4*)(pick4(in0, in1, in2, in3, inp) + (size_t)(s * 8 + row) * 128 + c4 * 4);
        *(float4*)(&buf[inp][row][c4 * 4]) = f;
    }
    __syncthreads();

    // norms: thread = (row32 = tid>>3) x (seg = tid&7), 16 els each; segs 0..3 = sh half
    {
        int row32 = tid >> 3, seg = tid & 7;
        const float* rp_ = &buf[row32 >> 3][row32 & 7][seg * 16];
        float ss = 0.0f;
        #pragma unroll
        for (int k = 0; k < 4; k++) {
            float4 x = *(const float4*)(rp_ + k * 4);
            ss = fmaf(x.x, x.x, fmaf(x.y, x.y, fmaf(x.z, x.z, fmaf(x.w, x.w, ss))));
        }
        ss += __shfl_xor(ss, 1); ss += __shfl_xor(ss, 2);   // sum own half
        float cross = __shfl_xor(ss, 4);                    // other half
        if (seg == 0) {
            iv[0][row32] = 1.0f / fmaxf(sqrtf(ss), EPS_N);          // sh
            iv[2][row32] = 1.0f / fmaxf(sqrtf(ss + cross), EPS_N);  // full
        }
        if (seg == 4) iv[1][row32] = 1.0f / fmaxf(sqrtf(ss), EPS_N); // pv
    }
    __syncthreads();

    // convert: thread = input(t>>6) x row((t>>3)&7) x 16-col chunk ((t&7)*16)
    {
        int input = tid >> 6, row = (tid >> 3) & 7, cs = (tid & 7) * 16;
        float scF = iv[2][input * 8 + row];
        float scH = iv[cs < 64 ? 0 : 1][input * 8 + row];
        unsigned short* zf = (unsigned short*)((char*)ws + ZF_BYTE) + (size_t)input * 524288 + (size_t)(s * 8 + row) * 128 + cs;
        unsigned short* zh = (unsigned short*)((char*)ws + ZH_BYTE) + (size_t)input * 524288 + (size_t)(s * 8 + row) * 128 + cs;
        const float* bp = &buf[input][row][cs];
        #pragma unroll
        for (int k4 = 0; k4 < 4; k4++) {
            float4 x = *(const float4*)(bp + k4 * 4);
            ushort4 of, oh;
            of.x = f2bf(x.x * scF); of.y = f2bf(x.y * scF); of.z = f2bf(x.z * scF); of.w = f2bf(x.w * scF);
            oh.x = f2bf(x.x * scH); oh.y = f2bf(x.y * scH); oh.z = f2bf(x.z * scH); oh.w = f2bf(x.w * scH);
            *(ushort4*)(zf + k4 * 4) = of;
            *(ushort4*)(zh + k4 * 4) = oh;
        }
    }

    // small dots: ortho (tid<48), contrastive pos (48..79), temporal pos (80..135)
    float val = 0.0f;
    int cat = -1;
    if (tid < 48) {
        const int oa[6]  = {0, 2, 1, 3, 0, 1};
        const int oaf[6] = {0, 0, 0, 0, 64, 64};
        const int ob[6]  = {0, 2, 1, 3, 2, 3};
        int term = tid >> 3, row = tid & 7;
        const float* A = &buf[oa[term]][row][oaf[term]];
        const float* B = &buf[ob[term]][row][64];
        float d = 0.0f;
        #pragma unroll
        for (int k = 0; k < 16; k++) {
            float4 x = *(const float4*)(A + k * 4);
            float4 y = *(const float4*)(B + k * 4);
            d = fmaf(x.x, y.x, fmaf(x.y, y.y, fmaf(x.z, y.z, fmaf(x.w, y.w, d))));
        }
        float ia = iv[oaf[term] ? 1 : 0][oa[term] * 8 + row];
        float ib = iv[1][ob[term] * 8 + row];
        val = fmaxf(d * ia * ib, 0.0f);
        cat = 2;
    } else if (tid < 80) {
        const int ca[4] = {0, 1, 0, 2}, cb[4] = {2, 3, 1, 3}, coff[4] = {0, 0, 64, 64};
        int call = (tid - 48) >> 3, row = (tid - 48) & 7;
        const float* A = &buf[ca[call]][row][coff[call]];
        const float* B = &buf[cb[call]][row][coff[call]];
        float d = 0.0f;
        #pragma unroll
        for (int k = 0; k < 16; k++) {
            float4 x = *(const float4*)(A + k * 4);
            float4 y = *(const float4*)(B + k * 4);
            d = fmaf(x.x, y.x, fmaf(x.y, y.y, fmaf(x.z, y.z, fmaf(x.w, y.w, d))));
        }
        int ivb = coff[call] ? 1 : 0;
        val = d * iv[ivb][ca[call] * 8 + row] * iv[ivb][cb[call] * 8 + row];
        cat = 0;
    } else if (tid < 136) {
        int u = tid - 80;
        int inp = u / 14, v = u % 14, pp = v >> 1, half = v & 1;
        int ra = (pp == 0) ? 1 : (pp + 1);
        const float* A = &buf[inp][ra][half * 64];
        const float* B = &buf[inp][0][half * 64];
        float d = 0.0f;
        #pragma unroll
        for (int k = 0; k < 16; k++) {
            float4 x = *(const float4*)(A + k * 4);
            float4 y = *(const float4*)(B + k * 4);
            d = fmaf(x.x, y.x, fmaf(x.y, y.y, fmaf(x.z, y.z, fmaf(x.w, y.w, d))));
        }
        float wgt = (pp == 0) ? 2.0f : 1.0f;
        val = d * wgt * iv[2][inp * 8 + ra] * iv[2][inp * 8];
        cat = 1;
    }
    if (cat >= 0) atomicAdd(&red[cat], val);
    __syncthreads();
    if (tid == 0) atomicAdd(ws + SLOT + 32 * 24, red[0]);
    if (tid == 1) atomicAdd(ws + SLOT + 32 * 25, red[1]);
    if (tid == 2) atomicAdd(ws + SLOT + 32 * (16 + (s & 7)), red[2]);
}

// ---------- unified symmetric gram + fused tail reduce ----------
// blocks [0,2176) temporal (4 inputs x 544), [2176,3456) contrastive (32 x 40)
__global__ __launch_bounds__(256) void k_gram(float* __restrict__ ws, float* __restrict__ out) {
    __shared__ short rowbuf[128 * 72];
    __shared__ short colbuf[128 * 72];
    __shared__ float tred[8];
    __shared__ int lastf;
    const int tid = threadIdx.x;
    const int b = blockIdx.x;

    bool folded;
    if (b < 2176) { int t = b % 544; folded = ((t >> 5) == 16 && (t & 31) >= 16); }
    else          { int t = (b - 2176) % 40; folded = ((t >> 3) == 4 && (t & 7) >= 4); }

    if (!folded) {
        const short* baseR;
        const short* baseC;
        int rstride, nk;
        float* rsR;
        float* rsC;
        bool diag;

        if (b < 2176) {
            int input = b / 544, t = b % 544;
            int j = t >> 5, i = t & 31;
            int rt = i, ct = (i + j) & 31;
            diag = (j == 0);
            const short* zf = (const short*)((const char*)ws + ZF_BYTE) + (size_t)input * 524288;
            baseR = zf + rt * 16384;
            baseC = zf + ct * 16384;
            rstride = 128; nk = 2;
            rsR = ws + RS_T + input * 4096 + rt * 128;
            rsC = ws + RS_T + input * 4096 + ct * 128;
        } else {
            int c = b - 2176;
            int callp = c / 40, t = c % 40;
            int j = t >> 3, i = t & 7;
            int call = callp >> 3, p = callp & 7;
            int rt = i, ct = (i + j) & 7;
            diag = (j == 0);
            const int ca[4] = {0, 1, 0, 2}, cb[4] = {2, 3, 1, 3}, coff[4] = {0, 0, 64, 64};
            const short* zh = (const short*)((const char*)ws + ZH_BYTE);
            int rbase = rt * 128, cbase = ct * 128;
            baseR = zh + (size_t)(rbase < 512 ? ca[call] : cb[call]) * 524288
                       + (size_t)((rbase & 511) * 8 + p) * 128 + coff[call];
            baseC = zh + (size_t)(cbase < 512 ? ca[call] : cb[call]) * 524288
                       + (size_t)((cbase & 511) * 8 + p) * 128 + coff[call];
            rstride = 1024; nk = 1;
            rsR = ws + RS_C + (call * 8 + p) * 1024 + rbase;
            rsC = ws + RS_C + (call * 8 + p) * 1024 + cbase;
        }

        floatx4 acc[4][4];
        #pragma unroll
        for (int ri = 0; ri < 4; ri++)
            #pragma unroll
            for (int ci = 0; ci < 4; ci++) acc[ri][ci] = (floatx4){0.f, 0.f, 0.f, 0.f};

        const int w = tid >> 6, lane = tid & 63, quad = (tid >> 4) & 3, l15 = tid & 15;
        const int wrow = (w >> 1) * 64, wcol = (w & 1) * 64;
        const short* bbuf = diag ? rowbuf : colbuf;

        for (int st = 0; st < nk; st++) {
            if (st) __syncthreads();
            const int kbase = st * 64;
            #pragma unroll
            for (int i = 0; i < 4; i++) {
                int e = tid + i * 256, r = e >> 3, k8 = e & 7;
                *(short8*)(rowbuf + r * 72 + k8 * 8) =
                    *(const short8*)(baseR + (size_t)r * rstride + kbase + k8 * 8);
                if (!diag)
                    *(short8*)(colbuf + r * 72 + k8 * 8) =
                        *(const short8*)(baseC + (size_t)r * rstride + kbase + k8 * 8);
            }
            __syncthreads();
            #pragma unroll
            for (int ks = 0; ks < 2; ks++) {
                short8 a[4], bb[4];
                int ko = ks * 32 + quad * 8;
                #pragma unroll
                for (int i = 0; i < 4; i++) {
                    a[i]  = *(const short8*)(rowbuf + (wrow + i * 16 + l15) * 72 + ko);
                    bb[i] = *(const short8*)(bbuf   + (wcol + i * 16 + l15) * 72 + ko);
                }
                #pragma unroll
                for (int ri = 0; ri < 4; ri++)
                    #pragma unroll
                    for (int ci = 0; ci < 4; ci++)
                        acc[ri][ci] = __builtin_amdgcn_mfma_f32_16x16x32_bf16(a[ri], bb[ci], acc[ri][ci], 0, 0, 0);
            }
        }

        if (diag) {
            #pragma unroll
            for (int ri = 0; ri < 4; ri++) {
                #pragma unroll
                for (int reg = 0; reg < 4; reg++) {
                    int rloc = wrow + ri * 16 + quad * 4 + reg;
                    float rp = 0.f;
                    #pragma unroll
                    for (int ci = 0; ci < 4; ci++) {
                        int cloc = wcol + ci * 16 + l15;
                        float ex = __builtin_amdgcn_exp2f(fmaf(acc[ri][ci][reg], C1EXP, -C1EXP));
                        rp += (cloc != rloc) ? ex : 0.f;   // exact diag exclusion
                    }
                    rp += __shfl_xor(rp, 1); rp += __shfl_xor(rp, 2);
                    rp += __shfl_xor(rp, 4); rp += __shfl_xor(rp, 8);
                    if (l15 == 0) atomicAdd(rsR + rloc, rp);
                }
            }
        } else {
            float colp[4] = {0.f, 0.f, 0.f, 0.f};
            #pragma unroll
            for (int ri = 0; ri < 4; ri++) {
                #pragma unroll
                for (int reg = 0; reg < 4; reg++) {
                    int rloc = wrow + ri * 16 + quad * 4 + reg;
                    float rp = 0.f;
                    #pragma unroll
                    for (int ci = 0; ci < 4; ci++) {
                        float ex = __builtin_amdgcn_exp2f(fmaf(acc[ri][ci][reg], C1EXP, -C1EXP));
                        rp += ex;
                        colp[ci] += ex;
                    }
                    rp += __shfl_xor(rp, 1); rp += __shfl_xor(rp, 2);
                    rp += __shfl_xor(rp, 4); rp += __shfl_xor(rp, 8);
                    if (l15 == 0) atomicAdd(rsR + rloc, rp);
                }
            }
            #pragma unroll
            for (int ci = 0; ci < 4; ci++) {           // transpose contribution
                colp[ci] += __shfl_xor(colp[ci], 16);
                colp[ci] += __shfl_xor(colp[ci], 32);
                if (lane < 16) atomicAdd(rsC + wcol + ci * 16 + l15, colp[ci]);
            }
        }
    }

    // ---- arrival + fused tail (logsum + final) ----
    // __syncthreads => s_waitcnt vmcnt(0): all rowsum atomics COMPLETED at the
    // device coherent point before the (relaxed, fence-free) counter RMW issues.
    __syncthreads();
    if (tid == 0) {
        int old = __hip_atomic_fetch_add((int*)(ws + SLOT + 32 * 26), 1,
                                         __ATOMIC_RELAXED, __HIP_MEMORY_SCOPE_AGENT);
        lastf = (old == NBLK_GRAM - 1);
    }
    __syncthreads();
    if (!lastf) return;

    // last block: read rowsums with relaxed agent-scope atomic loads (fresh values,
    // bypass this XCD's caches), 16384 temporal + 32768 contrastive logs.
    float acc_t = 0.f, acc_c = 0.f;
    for (int i = tid; i < 49152; i += 256) {
        float v = __hip_atomic_load(ws + RS_T + i, __ATOMIC_RELAXED, __HIP_MEMORY_SCOPE_AGENT);
        float l = __logf(v);
        if (i < 16384) acc_t += l; else acc_c += l;
    }
    #pragma unroll
    for (int m = 1; m < 64; m <<= 1) { acc_t += __shfl_xor(acc_t, m); acc_c += __shfl_xor(acc_c, m); }
    if ((tid & 63) == 0) { tred[tid >> 6] = acc_t; tred[4 + (tid >> 6)] = acc_c; }
    __syncthreads();
    if (tid == 0) {
        float ts = tred[0] + tred[1] + tred[2] + tred[3];
        float cs = tred[4] + tred[5] + tred[6] + tred[7];
        float os = 0.f;
        for (int i = 16; i < 24; i++) os += ws[SLOT + 32 * i];   // k_prep's writes: visible via launch boundary
        float posC = ws[SLOT + 32 * 24], posT = ws[SLOT + 32 * 25];
        out[0] = (cs + 32768.0f * INV_T - 2.0f * INV_T * posC) * (1.0f / 8192.0f)
               + (ts + 16384.0f * INV_T - INV_T * posT) * (1.0f / 4096.0f)
               + os * (1.0f / 4096.0f);
    }
}

extern "C" void kernel_launch(void* const* d_in, const int* in_sizes, int n_in,
                              void* d_out, int out_size, void* d_ws, size_t ws_size,
                              hipStream_t stream) {
    (void)in_sizes; (void)n_in; (void)out_size; (void)ws_size;
    const float* in0 = (const float*)d_in[0];
    const float* in1 = (const float*)d_in[1];
    const float* in2 = (const float*)d_in[2];
    const float* in3 = (const float*)d_in[3];
    float* ws = (float*)d_ws;
    float* out = (float*)d_out;

    hipLaunchKernelGGL(k_prep, dim3(512), dim3(256), 0, stream, in0, in1, in2, in3, ws);
    hipLaunchKernelGGL(k_gram, dim3(NBLK_GRAM), dim3(256), 0, stream, ws, out);
}

// Round 6
// 186.378 us; speedup vs baseline: 1.0449x; 1.0449x over previous
//
#include <hip/hip_runtime.h>
#include <math.h>

// CMCV3Loss: B=512, S=8, D=128, H=64. Inputs: 4 x (4096x128 fp32), seq_len.
// bf16-MFMA symmetric grams; loss_row = lse_{m!=n} - pos. Fixed max-shift:
// ex = exp((s-1)*INV_T) = exp2(fma(s, C1EXP, -C1EXP)) since s<=1 for normalized vecs.
// 2 launches: k_prep (norms+bf16 convert+small dots+zeroing), k_gram (+fused tail).
// R4/R5 lesson: 3456 same-address fetch_adds-with-return serialized ~70us at the
// MALL. Fix: 2-level arrival tree — 64 line-separated L1 counters (54 arrivals
// each), winners promote to one L2 counter (64 ops). RELAXED ordering (ACQ_REL
// per-block fences also regress); visibility via vmcnt-drain at __syncthreads +
// relaxed agent-scope tail loads (absmax 0.0 in R4 & R5 validates the scheme).
//
// ws float offsets:
#define CTR_L1 0        // 64 counters, stride 32 floats (128B lines)
#define CTR_L2 2048     // single second-level counter
#define RS_T   49152    // temporal rowsums [4][4096]
#define RS_C   65536    // contrastive rowsums [4 calls][8 p][1024]
#define SLOT   98304    // slots stride 32: 16..23 ortho, 24 posC, 25 posT
// ws byte offsets (bf16 arrays):
#define ZF_BYTE 397312   // znfull bf16 [4][4096][128]
#define ZH_BYTE 4591616  // znhalf bf16 [4][4096][128] (cols 0..63 sh-normed, 64..127 pv-normed)

#define INV_T 14.285714285714286f
#define C1EXP 20.609929155556627f   // INV_T * log2(e)
#define EPS_N 1e-8f
#define NBLK_GRAM 3456               // = 64 groups x 54

typedef __attribute__((ext_vector_type(8))) short short8;
typedef __attribute__((ext_vector_type(4))) float floatx4;

__device__ __forceinline__ const float* pick4(const float* a, const float* b,
                                              const float* c, const float* d, int i) {
    return i == 0 ? a : i == 1 ? b : i == 2 ? c : d;
}

__device__ __forceinline__ unsigned short f2bf(float x) {
    unsigned u = __float_as_uint(x);
    u += 0x7fff + ((u >> 16) & 1);
    return (unsigned short)(u >> 16);
}

// ---------- prep: zero counters+RS region, per-sequence norms, bf16 convert, ortho/pos dots ----------
// grid 512 (one per sequence), block 256.
__global__ __launch_bounds__(256) void k_prep(const float* __restrict__ in0, const float* __restrict__ in1,
                                              const float* __restrict__ in2, const float* __restrict__ in3,
                                              float* __restrict__ ws) {
    __shared__ float buf[4][8][128];    // 4 inputs x 8 rows of this sequence
    __shared__ float iv[3][32];         // [sh,pv,full] inverse norms, idx = input*8+row
    __shared__ float red[3];
    const int s = blockIdx.x;
    const int tid = threadIdx.x;

    int gid = s * 256 + tid;
    if (gid < 2080) ws[gid] = 0.0f;                 // arrival counters (L1 + L2)
    if (gid < 50176) ws[RS_T + gid] = 0.0f;         // rowsums + slots
    if (tid < 3) red[tid] = 0.0f;

    #pragma unroll
    for (int i = 0; i < 4; i++) {
        int e4 = tid + i * 256;
        int inp = e4 >> 8, row = (e4 >> 5) & 7, c4 = e4 & 31;
        float4 f = *(const float4*)(pick4(in0, in1, in2, in3, inp) + (size_t)(s * 8 + row) * 128 + c4 * 4);
        *(float4*)(&buf[inp][row][c4 * 4]) = f;
    }
    __syncthreads();

    // norms: thread = (row32 = tid>>3) x (seg = tid&7), 16 els each; segs 0..3 = sh half
    {
        int row32 = tid >> 3, seg = tid & 7;
        const float* rp_ = &buf[row32 >> 3][row32 & 7][seg * 16];
        float ss = 0.0f;
        #pragma unroll
        for (int k = 0; k < 4; k++) {
            float4 x = *(const float4*)(rp_ + k * 4);
            ss = fmaf(x.x, x.x, fmaf(x.y, x.y, fmaf(x.z, x.z, fmaf(x.w, x.w, ss))));
        }
        ss += __shfl_xor(ss, 1); ss += __shfl_xor(ss, 2);   // sum own half
        float cross = __shfl_xor(ss, 4);                    // other half
        if (seg == 0) {
            iv[0][row32] = 1.0f / fmaxf(sqrtf(ss), EPS_N);          // sh
            iv[2][row32] = 1.0f / fmaxf(sqrtf(ss + cross), EPS_N);  // full
        }
        if (seg == 4) iv[1][row32] = 1.0f / fmaxf(sqrtf(ss), EPS_N); // pv
    }
    __syncthreads();

    // convert: thread = input(t>>6) x row((t>>3)&7) x 16-col chunk ((t&7)*16)
    {
        int input = tid >> 6, row = (tid >> 3) & 7, cs = (tid & 7) * 16;
        float scF = iv[2][input * 8 + row];
        float scH = iv[cs < 64 ? 0 : 1][input * 8 + row];
        unsigned short* zf = (unsigned short*)((char*)ws + ZF_BYTE) + (size_t)input * 524288 + (size_t)(s * 8 + row) * 128 + cs;
        unsigned short* zh = (unsigned short*)((char*)ws + ZH_BYTE) + (size_t)input * 524288 + (size_t)(s * 8 + row) * 128 + cs;
        const float* bp = &buf[input][row][cs];
        #pragma unroll
        for (int k4 = 0; k4 < 4; k4++) {
            float4 x = *(const float4*)(bp + k4 * 4);
            ushort4 of, oh;
            of.x = f2bf(x.x * scF); of.y = f2bf(x.y * scF); of.z = f2bf(x.z * scF); of.w = f2bf(x.w * scF);
            oh.x = f2bf(x.x * scH); oh.y = f2bf(x.y * scH); oh.z = f2bf(x.z * scH); oh.w = f2bf(x.w * scH);
            *(ushort4*)(zf + k4 * 4) = of;
            *(ushort4*)(zh + k4 * 4) = oh;
        }
    }

    // small dots: ortho (tid<48), contrastive pos (48..79), temporal pos (80..135)
    float val = 0.0f;
    int cat = -1;
    if (tid < 48) {
        const int oa[6]  = {0, 2, 1, 3, 0, 1};
        const int oaf[6] = {0, 0, 0, 0, 64, 64};
        const int ob[6]  = {0, 2, 1, 3, 2, 3};
        int term = tid >> 3, row = tid & 7;
        const float* A = &buf[oa[term]][row][oaf[term]];
        const float* B = &buf[ob[term]][row][64];
        float d = 0.0f;
        #pragma unroll
        for (int k = 0; k < 16; k++) {
            float4 x = *(const float4*)(A + k * 4);
            float4 y = *(const float4*)(B + k * 4);
            d = fmaf(x.x, y.x, fmaf(x.y, y.y, fmaf(x.z, y.z, fmaf(x.w, y.w, d))));
        }
        float ia = iv[oaf[term] ? 1 : 0][oa[term] * 8 + row];
        float ib = iv[1][ob[term] * 8 + row];
        val = fmaxf(d * ia * ib, 0.0f);
        cat = 2;
    } else if (tid < 80) {
        const int ca[4] = {0, 1, 0, 2}, cb[4] = {2, 3, 1, 3}, coff[4] = {0, 0, 64, 64};
        int call = (tid - 48) >> 3, row = (tid - 48) & 7;
        const float* A = &buf[ca[call]][row][coff[call]];
        const float* B = &buf[cb[call]][row][coff[call]];
        float d = 0.0f;
        #pragma unroll
        for (int k = 0; k < 16; k++) {
            float4 x = *(const float4*)(A + k * 4);
            float4 y = *(const float4*)(B + k * 4);
            d = fmaf(x.x, y.x, fmaf(x.y, y.y, fmaf(x.z, y.z, fmaf(x.w, y.w, d))));
        }
        int ivb = coff[call] ? 1 : 0;
        val = d * iv[ivb][ca[call] * 8 + row] * iv[ivb][cb[call] * 8 + row];
        cat = 0;
    } else if (tid < 136) {
        int u = tid - 80;
        int inp = u / 14, v = u % 14, pp = v >> 1, half = v & 1;
        int ra = (pp == 0) ? 1 : (pp + 1);
        const float* A = &buf[inp][ra][half * 64];
        const float* B = &buf[inp][0][half * 64];
        float d = 0.0f;
        #pragma unroll
        for (int k = 0; k < 16; k++) {
            float4 x = *(const float4*)(A + k * 4);
            float4 y = *(const float4*)(B + k * 4);
            d = fmaf(x.x, y.x, fmaf(x.y, y.y, fmaf(x.z, y.z, fmaf(x.w, y.w, d))));
        }
        float wgt = (pp == 0) ? 2.0f : 1.0f;
        val = d * wgt * iv[2][inp * 8 + ra] * iv[2][inp * 8];
        cat = 1;
    }
    if (cat >= 0) atomicAdd(&red[cat], val);
    __syncthreads();
    if (tid == 0) atomicAdd(ws + SLOT + 32 * 24, red[0]);
    if (tid == 1) atomicAdd(ws + SLOT + 32 * 25, red[1]);
    if (tid == 2) atomicAdd(ws + SLOT + 32 * (16 + (s & 7)), red[2]);
}

// ---------- unified symmetric gram + fused tail reduce ----------
// blocks [0,2176) temporal (4 inputs x 544), [2176,3456) contrastive (32 x 40)
__global__ __launch_bounds__(256) void k_gram(float* __restrict__ ws, float* __restrict__ out) {
    __shared__ short rowbuf[128 * 72];
    __shared__ short colbuf[128 * 72];
    __shared__ float tred[8];
    __shared__ int lastf;
    const int tid = threadIdx.x;
    const int b = blockIdx.x;

    bool folded;
    if (b < 2176) { int t = b % 544; folded = ((t >> 5) == 16 && (t & 31) >= 16); }
    else          { int t = (b - 2176) % 40; folded = ((t >> 3) == 4 && (t & 7) >= 4); }

    if (!folded) {
        const short* baseR;
        const short* baseC;
        int rstride, nk;
        float* rsR;
        float* rsC;
        bool diag;

        if (b < 2176) {
            int input = b / 544, t = b % 544;
            int j = t >> 5, i = t & 31;
            int rt = i, ct = (i + j) & 31;
            diag = (j == 0);
            const short* zf = (const short*)((const char*)ws + ZF_BYTE) + (size_t)input * 524288;
            baseR = zf + rt * 16384;
            baseC = zf + ct * 16384;
            rstride = 128; nk = 2;
            rsR = ws + RS_T + input * 4096 + rt * 128;
            rsC = ws + RS_T + input * 4096 + ct * 128;
        } else {
            int c = b - 2176;
            int callp = c / 40, t = c % 40;
            int j = t >> 3, i = t & 7;
            int call = callp >> 3, p = callp & 7;
            int rt = i, ct = (i + j) & 7;
            diag = (j == 0);
            const int ca[4] = {0, 1, 0, 2}, cb[4] = {2, 3, 1, 3}, coff[4] = {0, 0, 64, 64};
            const short* zh = (const short*)((const char*)ws + ZH_BYTE);
            int rbase = rt * 128, cbase = ct * 128;
            baseR = zh + (size_t)(rbase < 512 ? ca[call] : cb[call]) * 524288
                       + (size_t)((rbase & 511) * 8 + p) * 128 + coff[call];
            baseC = zh + (size_t)(cbase < 512 ? ca[call] : cb[call]) * 524288
                       + (size_t)((cbase & 511) * 8 + p) * 128 + coff[call];
            rstride = 1024; nk = 1;
            rsR = ws + RS_C + (call * 8 + p) * 1024 + rbase;
            rsC = ws + RS_C + (call * 8 + p) * 1024 + cbase;
        }

        floatx4 acc[4][4];
        #pragma unroll
        for (int ri = 0; ri < 4; ri++)
            #pragma unroll
            for (int ci = 0; ci < 4; ci++) acc[ri][ci] = (floatx4){0.f, 0.f, 0.f, 0.f};

        const int w = tid >> 6, lane = tid & 63, quad = (tid >> 4) & 3, l15 = tid & 15;
        const int wrow = (w >> 1) * 64, wcol = (w & 1) * 64;
        const short* bbuf = diag ? rowbuf : colbuf;

        for (int st = 0; st < nk; st++) {
            if (st) __syncthreads();
            const int kbase = st * 64;
            #pragma unroll
            for (int i = 0; i < 4; i++) {
                int e = tid + i * 256, r = e >> 3, k8 = e & 7;
                *(short8*)(rowbuf + r * 72 + k8 * 8) =
                    *(const short8*)(baseR + (size_t)r * rstride + kbase + k8 * 8);
                if (!diag)
                    *(short8*)(colbuf + r * 72 + k8 * 8) =
                        *(const short8*)(baseC + (size_t)r * rstride + kbase + k8 * 8);
            }
            __syncthreads();
            #pragma unroll
            for (int ks = 0; ks < 2; ks++) {
                short8 a[4], bb[4];
                int ko = ks * 32 + quad * 8;
                #pragma unroll
                for (int i = 0; i < 4; i++) {
                    a[i]  = *(const short8*)(rowbuf + (wrow + i * 16 + l15) * 72 + ko);
                    bb[i] = *(const short8*)(bbuf   + (wcol + i * 16 + l15) * 72 + ko);
                }
                #pragma unroll
                for (int ri = 0; ri < 4; ri++)
                    #pragma unroll
                    for (int ci = 0; ci < 4; ci++)
                        acc[ri][ci] = __builtin_amdgcn_mfma_f32_16x16x32_bf16(a[ri], bb[ci], acc[ri][ci], 0, 0, 0);
            }
        }

        if (diag) {
            #pragma unroll
            for (int ri = 0; ri < 4; ri++) {
                #pragma unroll
                for (int reg = 0; reg < 4; reg++) {
                    int rloc = wrow + ri * 16 + quad * 4 + reg;
                    float rp = 0.f;
                    #pragma unroll
                    for (int ci = 0; ci < 4; ci++) {
                        int cloc = wcol + ci * 16 + l15;
                        float ex = __builtin_amdgcn_exp2f(fmaf(acc[ri][ci][reg], C1EXP, -C1EXP));
                        rp += (cloc != rloc) ? ex : 0.f;   // exact diag exclusion
                    }
                    rp += __shfl_xor(rp, 1); rp += __shfl_xor(rp, 2);
                    rp += __shfl_xor(rp, 4); rp += __shfl_xor(rp, 8);
                    if (l15 == 0) atomicAdd(rsR + rloc, rp);
                }
            }
        } else {
            float colp[4] = {0.f, 0.f, 0.f, 0.f};
            #pragma unroll
            for (int ri = 0; ri < 4; ri++) {
                #pragma unroll
                for (int reg = 0; reg < 4; reg++) {
                    int rloc = wrow + ri * 16 + quad * 4 + reg;
                    float rp = 0.f;
                    #pragma unroll
                    for (int ci = 0; ci < 4; ci++) {
                        float ex = __builtin_amdgcn_exp2f(fmaf(acc[ri][ci][reg], C1EXP, -C1EXP));
                        rp += ex;
                        colp[ci] += ex;
                    }
                    rp += __shfl_xor(rp, 1); rp += __shfl_xor(rp, 2);
                    rp += __shfl_xor(rp, 4); rp += __shfl_xor(rp, 8);
                    if (l15 == 0) atomicAdd(rsR + rloc, rp);
                }
            }
            #pragma unroll
            for (int ci = 0; ci < 4; ci++) {           // transpose contribution
                colp[ci] += __shfl_xor(colp[ci], 16);
                colp[ci] += __shfl_xor(colp[ci], 32);
                if (lane < 16) atomicAdd(rsC + wcol + ci * 16 + l15, colp[ci]);
            }
        }
    }

    // ---- hierarchical arrival + fused tail (logsum + final) ----
    // __syncthreads => s_waitcnt vmcnt(0): this block's rowsum atomics completed
    // at the coherent point before the (relaxed) counter RMW issues.
    __syncthreads();
    if (tid == 0) {
        int last = 0;
        int o1 = __hip_atomic_fetch_add((int*)(ws + CTR_L1 + 32 * (b & 63)), 1,
                                        __ATOMIC_RELAXED, __HIP_MEMORY_SCOPE_AGENT);
        if (o1 == 53) {                               // all 54 blocks of this class done
            int o2 = __hip_atomic_fetch_add((int*)(ws + CTR_L2), 1,
                                            __ATOMIC_RELAXED, __HIP_MEMORY_SCOPE_AGENT);
            last = (o2 == 63);                        // all 64 classes done
        }
        lastf = last;
    }
    __syncthreads();
    if (!lastf) return;

    // last block: relaxed agent-scope atomic loads (fresh values, bypass stale caches)
    float acc_t = 0.f, acc_c = 0.f;
    for (int i = tid; i < 49152; i += 256) {
        float v = __hip_atomic_load(ws + RS_T + i, __ATOMIC_RELAXED, __HIP_MEMORY_SCOPE_AGENT);
        float l = __logf(v);
        if (i < 16384) acc_t += l; else acc_c += l;
    }
    #pragma unroll
    for (int m = 1; m < 64; m <<= 1) { acc_t += __shfl_xor(acc_t, m); acc_c += __shfl_xor(acc_c, m); }
    if ((tid & 63) == 0) { tred[tid >> 6] = acc_t; tred[4 + (tid >> 6)] = acc_c; }
    __syncthreads();
    if (tid == 0) {
        float ts = tred[0] + tred[1] + tred[2] + tred[3];
        float cs = tred[4] + tred[5] + tred[6] + tred[7];
        float os = 0.f;
        for (int i = 16; i < 24; i++)
            os += __hip_atomic_load(ws + SLOT + 32 * i, __ATOMIC_RELAXED, __HIP_MEMORY_SCOPE_AGENT);
        float posC = __hip_atomic_load(ws + SLOT + 32 * 24, __ATOMIC_RELAXED, __HIP_MEMORY_SCOPE_AGENT);
        float posT = __hip_atomic_load(ws + SLOT + 32 * 25, __ATOMIC_RELAXED, __HIP_MEMORY_SCOPE_AGENT);
        out[0] = (cs + 32768.0f * INV_T - 2.0f * INV_T * posC) * (1.0f / 8192.0f)
               + (ts + 16384.0f * INV_T - INV_T * posT) * (1.0f / 4096.0f)
               + os * (1.0f / 4096.0f);
    }
}

extern "C" void kernel_launch(void* const* d_in, const int* in_sizes, int n_in,
                              void* d_out, int out_size, void* d_ws, size_t ws_size,
                              hipStream_t stream) {
    (void)in_sizes; (void)n_in; (void)out_size; (void)ws_size;
    const float* in0 = (const float*)d_in[0];
    const float* in1 = (const float*)d_in[1];
    const float* in2 = (const float*)d_in[2];
    const float* in3 = (const float*)d_in[3];
    float* ws = (float*)d_ws;
    float* out = (float*)d_out;

    hipLaunchKernelGGL(k_prep, dim3(512), dim3(256), 0, stream, in0, in1, in2, in3, ws);
    hipLaunchKernelGGL(k_gram, dim3(NBLK_GRAM), dim3(256), 0, stream, ws, out);
}

// Round 7
// 133.834 us; speedup vs baseline: 1.4551x; 1.3926x over previous
//
#include <hip/hip_runtime.h>
#include <math.h>

// CMCV3Loss: B=512, S=8, D=128, H=64. Inputs: 4 x (4096x128 fp32), seq_len.
// bf16-MFMA symmetric grams; loss_row = lse_{m!=n} - pos. Fixed max-shift:
// ex = exp((s-1)*INV_T) = exp2(fma(s, C1EXP, -C1EXP)) since s<=1 for normalized vecs.
// 3 launches: k_prep (norms+bf16+small dots+zeroing), k_gram (pure), k_tail (logsum+final).
// R4-R6 lesson: a single-block fused tail doing 49K agent-scope loads is
// latency-bound (~55us serial). Tail must be grid-parallel: k_tail uses 192
// blocks (1 value/thread, plain loads — visibility via launch boundary, the
// R3-validated scheme), plus a small 2-level arrival (24 RMWs/address) so its
// last block emits out[0].
//
// ws float offsets:
#define CTR_L1 0        // 8 counters, stride 32 floats (k_tail arrival)
#define CTR_L2 2048     // single second-level counter
#define RS_T   49152    // temporal rowsums [4][4096]
#define RS_C   65536    // contrastive rowsums [4 calls][8 p][1024]
#define SLOT   98304    // slots stride 32: 0..7 c-log, 8..15 t-log, 16..23 ortho, 24 posC, 25 posT
// ws byte offsets (bf16 arrays):
#define ZF_BYTE 397312   // znfull bf16 [4][4096][128]
#define ZH_BYTE 4591616  // znhalf bf16 [4][4096][128] (cols 0..63 sh-normed, 64..127 pv-normed)

#define INV_T 14.285714285714286f
#define C1EXP 20.609929155556627f   // INV_T * log2(e)
#define EPS_N 1e-8f
#define NBLK_TAIL 192                // 8 groups x 24

typedef __attribute__((ext_vector_type(8))) short short8;
typedef __attribute__((ext_vector_type(4))) float floatx4;

__device__ __forceinline__ const float* pick4(const float* a, const float* b,
                                              const float* c, const float* d, int i) {
    return i == 0 ? a : i == 1 ? b : i == 2 ? c : d;
}

__device__ __forceinline__ unsigned short f2bf(float x) {
    unsigned u = __float_as_uint(x);
    u += 0x7fff + ((u >> 16) & 1);
    return (unsigned short)(u >> 16);
}

// ---------- prep: zero counters+RS region, per-sequence norms, bf16 convert, ortho/pos dots ----------
// grid 512 (one per sequence), block 256.
__global__ __launch_bounds__(256) void k_prep(const float* __restrict__ in0, const float* __restrict__ in1,
                                              const float* __restrict__ in2, const float* __restrict__ in3,
                                              float* __restrict__ ws) {
    __shared__ float buf[4][8][128];    // 4 inputs x 8 rows of this sequence
    __shared__ float iv[3][32];         // [sh,pv,full] inverse norms, idx = input*8+row
    __shared__ float red[3];
    const int s = blockIdx.x;
    const int tid = threadIdx.x;

    int gid = s * 256 + tid;
    if (gid < 2080) ws[gid] = 0.0f;                 // arrival counters (L1 + L2)
    if (gid < 50176) ws[RS_T + gid] = 0.0f;         // rowsums + slots
    if (tid < 3) red[tid] = 0.0f;

    #pragma unroll
    for (int i = 0; i < 4; i++) {
        int e4 = tid + i * 256;
        int inp = e4 >> 8, row = (e4 >> 5) & 7, c4 = e4 & 31;
        float4 f = *(const float4*)(pick4(in0, in1, in2, in3, inp) + (size_t)(s * 8 + row) * 128 + c4 * 4);
        *(float4*)(&buf[inp][row][c4 * 4]) = f;
    }
    __syncthreads();

    // norms: thread = (row32 = tid>>3) x (seg = tid&7), 16 els each; segs 0..3 = sh half
    {
        int row32 = tid >> 3, seg = tid & 7;
        const float* rp_ = &buf[row32 >> 3][row32 & 7][seg * 16];
        float ss = 0.0f;
        #pragma unroll
        for (int k = 0; k < 4; k++) {
            float4 x = *(const float4*)(rp_ + k * 4);
            ss = fmaf(x.x, x.x, fmaf(x.y, x.y, fmaf(x.z, x.z, fmaf(x.w, x.w, ss))));
        }
        ss += __shfl_xor(ss, 1); ss += __shfl_xor(ss, 2);   // sum own half
        float cross = __shfl_xor(ss, 4);                    // other half
        if (seg == 0) {
            iv[0][row32] = 1.0f / fmaxf(sqrtf(ss), EPS_N);          // sh
            iv[2][row32] = 1.0f / fmaxf(sqrtf(ss + cross), EPS_N);  // full
        }
        if (seg == 4) iv[1][row32] = 1.0f / fmaxf(sqrtf(ss), EPS_N); // pv
    }
    __syncthreads();

    // convert: thread = input(t>>6) x row((t>>3)&7) x 16-col chunk ((t&7)*16)
    {
        int input = tid >> 6, row = (tid >> 3) & 7, cs = (tid & 7) * 16;
        float scF = iv[2][input * 8 + row];
        float scH = iv[cs < 64 ? 0 : 1][input * 8 + row];
        unsigned short* zf = (unsigned short*)((char*)ws + ZF_BYTE) + (size_t)input * 524288 + (size_t)(s * 8 + row) * 128 + cs;
        unsigned short* zh = (unsigned short*)((char*)ws + ZH_BYTE) + (size_t)input * 524288 + (size_t)(s * 8 + row) * 128 + cs;
        const float* bp = &buf[input][row][cs];
        #pragma unroll
        for (int k4 = 0; k4 < 4; k4++) {
            float4 x = *(const float4*)(bp + k4 * 4);
            ushort4 of, oh;
            of.x = f2bf(x.x * scF); of.y = f2bf(x.y * scF); of.z = f2bf(x.z * scF); of.w = f2bf(x.w * scF);
            oh.x = f2bf(x.x * scH); oh.y = f2bf(x.y * scH); oh.z = f2bf(x.z * scH); oh.w = f2bf(x.w * scH);
            *(ushort4*)(zf + k4 * 4) = of;
            *(ushort4*)(zh + k4 * 4) = oh;
        }
    }

    // small dots: ortho (tid<48), contrastive pos (48..79), temporal pos (80..135)
    float val = 0.0f;
    int cat = -1;
    if (tid < 48) {
        const int oa[6]  = {0, 2, 1, 3, 0, 1};
        const int oaf[6] = {0, 0, 0, 0, 64, 64};
        const int ob[6]  = {0, 2, 1, 3, 2, 3};
        int term = tid >> 3, row = tid & 7;
        const float* A = &buf[oa[term]][row][oaf[term]];
        const float* B = &buf[ob[term]][row][64];
        float d = 0.0f;
        #pragma unroll
        for (int k = 0; k < 16; k++) {
            float4 x = *(const float4*)(A + k * 4);
            float4 y = *(const float4*)(B + k * 4);
            d = fmaf(x.x, y.x, fmaf(x.y, y.y, fmaf(x.z, y.z, fmaf(x.w, y.w, d))));
        }
        float ia = iv[oaf[term] ? 1 : 0][oa[term] * 8 + row];
        float ib = iv[1][ob[term] * 8 + row];
        val = fmaxf(d * ia * ib, 0.0f);
        cat = 2;
    } else if (tid < 80) {
        const int ca[4] = {0, 1, 0, 2}, cb[4] = {2, 3, 1, 3}, coff[4] = {0, 0, 64, 64};
        int call = (tid - 48) >> 3, row = (tid - 48) & 7;
        const float* A = &buf[ca[call]][row][coff[call]];
        const float* B = &buf[cb[call]][row][coff[call]];
        float d = 0.0f;
        #pragma unroll
        for (int k = 0; k < 16; k++) {
            float4 x = *(const float4*)(A + k * 4);
            float4 y = *(const float4*)(B + k * 4);
            d = fmaf(x.x, y.x, fmaf(x.y, y.y, fmaf(x.z, y.z, fmaf(x.w, y.w, d))));
        }
        int ivb = coff[call] ? 1 : 0;
        val = d * iv[ivb][ca[call] * 8 + row] * iv[ivb][cb[call] * 8 + row];
        cat = 0;
    } else if (tid < 136) {
        int u = tid - 80;
        int inp = u / 14, v = u % 14, pp = v >> 1, half = v & 1;
        int ra = (pp == 0) ? 1 : (pp + 1);
        const float* A = &buf[inp][ra][half * 64];
        const float* B = &buf[inp][0][half * 64];
        float d = 0.0f;
        #pragma unroll
        for (int k = 0; k < 16; k++) {
            float4 x = *(const float4*)(A + k * 4);
            float4 y = *(const float4*)(B + k * 4);
            d = fmaf(x.x, y.x, fmaf(x.y, y.y, fmaf(x.z, y.z, fmaf(x.w, y.w, d))));
        }
        float wgt = (pp == 0) ? 2.0f : 1.0f;
        val = d * wgt * iv[2][inp * 8 + ra] * iv[2][inp * 8];
        cat = 1;
    }
    if (cat >= 0) atomicAdd(&red[cat], val);
    __syncthreads();
    if (tid == 0) atomicAdd(ws + SLOT + 32 * 24, red[0]);
    if (tid == 1) atomicAdd(ws + SLOT + 32 * 25, red[1]);
    if (tid == 2) atomicAdd(ws + SLOT + 32 * (16 + (s & 7)), red[2]);
}

// ---------- unified symmetric gram (pure — R3 hot path, measured 56us) ----------
// blocks [0,2176) temporal (4 inputs x 544), [2176,3456) contrastive (32 x 40)
__global__ __launch_bounds__(256) void k_gram(float* __restrict__ ws) {
    __shared__ short rowbuf[128 * 72];
    __shared__ short colbuf[128 * 72];
    const int tid = threadIdx.x;
    const int b = blockIdx.x;

    const short* baseR;
    const short* baseC;
    int rstride, nk;
    float* rsR;
    float* rsC;
    bool diag;

    if (b < 2176) {
        int input = b / 544, t = b % 544;
        int j = t >> 5, i = t & 31;
        if (j == 16 && i >= 16) return;          // folded duplicate
        int rt = i, ct = (i + j) & 31;
        diag = (j == 0);
        const short* zf = (const short*)((const char*)ws + ZF_BYTE) + (size_t)input * 524288;
        baseR = zf + rt * 16384;
        baseC = zf + ct * 16384;
        rstride = 128; nk = 2;
        rsR = ws + RS_T + input * 4096 + rt * 128;
        rsC = ws + RS_T + input * 4096 + ct * 128;
    } else {
        int c = b - 2176;
        int callp = c / 40, t = c % 40;
        int j = t >> 3, i = t & 7;
        if (j == 4 && i >= 4) return;
        int call = callp >> 3, p = callp & 7;
        int rt = i, ct = (i + j) & 7;
        diag = (j == 0);
        const int ca[4] = {0, 1, 0, 2}, cb[4] = {2, 3, 1, 3}, coff[4] = {0, 0, 64, 64};
        const short* zh = (const short*)((const char*)ws + ZH_BYTE);
        int rbase = rt * 128, cbase = ct * 128;
        baseR = zh + (size_t)(rbase < 512 ? ca[call] : cb[call]) * 524288
                   + (size_t)((rbase & 511) * 8 + p) * 128 + coff[call];
        baseC = zh + (size_t)(cbase < 512 ? ca[call] : cb[call]) * 524288
                   + (size_t)((cbase & 511) * 8 + p) * 128 + coff[call];
        rstride = 1024; nk = 1;
        rsR = ws + RS_C + (call * 8 + p) * 1024 + rbase;
        rsC = ws + RS_C + (call * 8 + p) * 1024 + cbase;
    }

    floatx4 acc[4][4];
    #pragma unroll
    for (int ri = 0; ri < 4; ri++)
        #pragma unroll
        for (int ci = 0; ci < 4; ci++) acc[ri][ci] = (floatx4){0.f, 0.f, 0.f, 0.f};

    const int w = tid >> 6, lane = tid & 63, quad = (tid >> 4) & 3, l15 = tid & 15;
    const int wrow = (w >> 1) * 64, wcol = (w & 1) * 64;
    const short* bbuf = diag ? rowbuf : colbuf;

    for (int st = 0; st < nk; st++) {
        if (st) __syncthreads();
        const int kbase = st * 64;
        #pragma unroll
        for (int i = 0; i < 4; i++) {
            int e = tid + i * 256, r = e >> 3, k8 = e & 7;
            *(short8*)(rowbuf + r * 72 + k8 * 8) =
                *(const short8*)(baseR + (size_t)r * rstride + kbase + k8 * 8);
            if (!diag)
                *(short8*)(colbuf + r * 72 + k8 * 8) =
                    *(const short8*)(baseC + (size_t)r * rstride + kbase + k8 * 8);
        }
        __syncthreads();
        #pragma unroll
        for (int ks = 0; ks < 2; ks++) {
            short8 a[4], bb[4];
            int ko = ks * 32 + quad * 8;
            #pragma unroll
            for (int i = 0; i < 4; i++) {
                a[i]  = *(const short8*)(rowbuf + (wrow + i * 16 + l15) * 72 + ko);
                bb[i] = *(const short8*)(bbuf   + (wcol + i * 16 + l15) * 72 + ko);
            }
            #pragma unroll
            for (int ri = 0; ri < 4; ri++)
                #pragma unroll
                for (int ci = 0; ci < 4; ci++)
                    acc[ri][ci] = __builtin_amdgcn_mfma_f32_16x16x32_bf16(a[ri], bb[ci], acc[ri][ci], 0, 0, 0);
        }
    }

    if (diag) {
        #pragma unroll
        for (int ri = 0; ri < 4; ri++) {
            #pragma unroll
            for (int reg = 0; reg < 4; reg++) {
                int rloc = wrow + ri * 16 + quad * 4 + reg;
                float rp = 0.f;
                #pragma unroll
                for (int ci = 0; ci < 4; ci++) {
                    int cloc = wcol + ci * 16 + l15;
                    float ex = __builtin_amdgcn_exp2f(fmaf(acc[ri][ci][reg], C1EXP, -C1EXP));
                    rp += (cloc != rloc) ? ex : 0.f;   // exact diag exclusion
                }
                rp += __shfl_xor(rp, 1); rp += __shfl_xor(rp, 2);
                rp += __shfl_xor(rp, 4); rp += __shfl_xor(rp, 8);
                if (l15 == 0) atomicAdd(rsR + rloc, rp);
            }
        }
    } else {
        float colp[4] = {0.f, 0.f, 0.f, 0.f};
        #pragma unroll
        for (int ri = 0; ri < 4; ri++) {
            #pragma unroll
            for (int reg = 0; reg < 4; reg++) {
                int rloc = wrow + ri * 16 + quad * 4 + reg;
                float rp = 0.f;
                #pragma unroll
                for (int ci = 0; ci < 4; ci++) {
                    float ex = __builtin_amdgcn_exp2f(fmaf(acc[ri][ci][reg], C1EXP, -C1EXP));
                    rp += ex;
                    colp[ci] += ex;
                }
                rp += __shfl_xor(rp, 1); rp += __shfl_xor(rp, 2);
                rp += __shfl_xor(rp, 4); rp += __shfl_xor(rp, 8);
                if (l15 == 0) atomicAdd(rsR + rloc, rp);
            }
        }
        #pragma unroll
        for (int ci = 0; ci < 4; ci++) {           // transpose contribution
            colp[ci] += __shfl_xor(colp[ci], 16);
            colp[ci] += __shfl_xor(colp[ci], 32);
            if (lane < 16) atomicAdd(rsC + wcol + ci * 16 + l15, colp[ci]);
        }
    }
}

// ---------- tail: grid-parallel logsum + arrival-gated final ----------
// 192 blocks x 256: one rowsum value per thread (plain loads; launch boundary
// guarantees visibility of k_gram's atomics — R3-validated).
__global__ __launch_bounds__(256) void k_tail(float* __restrict__ ws, float* __restrict__ out) {
    __shared__ float tred[4];
    __shared__ int lastf;
    const int tid = threadIdx.x;
    const int b = blockIdx.x;
    const int idx = b * 256 + tid;       // blocks 0..63 temporal, 64..191 contrastive

    float l = __logf(ws[RS_T + idx]);
    #pragma unroll
    for (int m = 1; m < 64; m <<= 1) l += __shfl_xor(l, m);
    if ((tid & 63) == 0) tred[tid >> 6] = l;
    __syncthreads();
    if (tid == 0) {
        float bs = tred[0] + tred[1] + tred[2] + tred[3];
        int slot = (idx < 16384) ? (8 + (b & 7)) : (b & 7);
        atomicAdd(ws + SLOT + 32 * slot, bs);
    }
    // __syncthreads drains vmcnt(0): tid0's slot atomic completed at the coherent
    // point before the counter RMW issues (validated pattern, absmax 0.0 x3).
    __syncthreads();
    if (tid == 0) {
        int last = 0;
        int o1 = __hip_atomic_fetch_add((int*)(ws + CTR_L1 + 32 * (b & 7)), 1,
                                        __ATOMIC_RELAXED, __HIP_MEMORY_SCOPE_AGENT);
        if (o1 == 23) {                                  // 24 arrivals per group
            int o2 = __hip_atomic_fetch_add((int*)(ws + CTR_L2), 1,
                                            __ATOMIC_RELAXED, __HIP_MEMORY_SCOPE_AGENT);
            last = (o2 == 7);                            // 8 groups
        }
        lastf = last;
    }
    __syncthreads();
    if (!lastf) return;

    if (tid < 64) {                      // lane-parallel final combine
        float v2 = 0.0f;
        if (tid < 26) {
            float x = __hip_atomic_load(ws + SLOT + 32 * tid, __ATOMIC_RELAXED, __HIP_MEMORY_SCOPE_AGENT);
            float wgt;
            if (tid < 8)       wgt = 1.0f / 8192.0f;             // c-log
            else if (tid < 24) wgt = 1.0f / 4096.0f;             // t-log + ortho
            else if (tid == 24) wgt = -2.0f * INV_T / 8192.0f;   // posC
            else                wgt = -INV_T / 4096.0f;          // posT
            v2 = x * wgt;
        }
        #pragma unroll
        for (int m = 1; m < 64; m <<= 1) v2 += __shfl_xor(v2, m);
        if (tid == 0) out[0] = v2 + 8.0f * INV_T;   // 32768*INV_T/8192 + 16384*INV_T/4096
    }
}

extern "C" void kernel_launch(void* const* d_in, const int* in_sizes, int n_in,
                              void* d_out, int out_size, void* d_ws, size_t ws_size,
                              hipStream_t stream) {
    (void)in_sizes; (void)n_in; (void)out_size; (void)ws_size;
    const float* in0 = (const float*)d_in[0];
    const float* in1 = (const float*)d_in[1];
    const float* in2 = (const float*)d_in[2];
    const float* in3 = (const float*)d_in[3];
    float* ws = (float*)d_ws;
    float* out = (float*)d_out;

    hipLaunchKernelGGL(k_prep, dim3(512), dim3(256), 0, stream, in0, in1, in2, in3, ws);
    hipLaunchKernelGGL(k_gram, dim3(3456), dim3(256), 0, stream, ws);
    hipLaunchKernelGGL(k_tail, dim3(NBLK_TAIL), dim3(256), 0, stream, ws, out);
}

// Round 8
// 125.628 us; speedup vs baseline: 1.5502x; 1.0653x over previous
//
#include <hip/hip_runtime.h>
#include <math.h>

// CMCV3Loss: B=512, S=8, D=128, H=64. Inputs: 4 x (4096x128 fp32), seq_len.
// bf16-MFMA symmetric grams; loss_row = lse_{m!=n} - pos. Fixed max-shift:
// ex = exp((s-1)*INV_T) = exp2(fma(s, C1EXP, -C1EXP)) since s<=1 for normalized vecs.
// 3 launches: k_prep, k_gram, k_tail.
// R8: k_gram staging via global_load_lds width=16 (async direct-to-LDS, no VGPR
// round trip / no ds_writes — which held 8-way write bank conflicts). LDS pad
// dropped (DMA needs contiguous lane x 16B); bank spread via XOR chunk swizzle
// c' = c ^ (r&7) applied on the global source side and in ds_read addressing
// (2-way aliasing = free, m136).
//
// ws float offsets:
#define CTR_L1 0        // 8 counters, stride 32 floats (k_tail arrival)
#define CTR_L2 2048     // single second-level counter
#define RS_T   49152    // temporal rowsums [4][4096]
#define RS_C   65536    // contrastive rowsums [4 calls][8 p][1024]
#define SLOT   98304    // slots stride 32: 0..7 c-log, 8..15 t-log, 16..23 ortho, 24 posC, 25 posT
// ws byte offsets (bf16 arrays):
#define ZF_BYTE 397312   // znfull bf16 [4][4096][128]
#define ZH_BYTE 4591616  // znhalf bf16 [4][4096][128] (cols 0..63 sh-normed, 64..127 pv-normed)

#define INV_T 14.285714285714286f
#define C1EXP 20.609929155556627f   // INV_T * log2(e)
#define EPS_N 1e-8f
#define NBLK_TAIL 192                // 8 groups x 24

typedef __attribute__((ext_vector_type(8))) short short8;
typedef __attribute__((ext_vector_type(4))) float floatx4;

__device__ __forceinline__ const float* pick4(const float* a, const float* b,
                                              const float* c, const float* d, int i) {
    return i == 0 ? a : i == 1 ? b : i == 2 ? c : d;
}

__device__ __forceinline__ unsigned short f2bf(float x) {
    unsigned u = __float_as_uint(x);
    u += 0x7fff + ((u >> 16) & 1);
    return (unsigned short)(u >> 16);
}

__device__ __forceinline__ void load_lds16(const short* g, short* lds) {
    // lds must be wave-uniform; lane j deposits 16B at lds + j*16.
    __builtin_amdgcn_global_load_lds(
        (const __attribute__((address_space(1))) void*)g,
        (__attribute__((address_space(3))) void*)lds,
        16, 0, 0);
}

// ---------- prep: zero counters+RS region, per-sequence norms, bf16 convert, ortho/pos dots ----------
// grid 512 (one per sequence), block 256.
__global__ __launch_bounds__(256) void k_prep(const float* __restrict__ in0, const float* __restrict__ in1,
                                              const float* __restrict__ in2, const float* __restrict__ in3,
                                              float* __restrict__ ws) {
    __shared__ float buf[4][8][128];    // 4 inputs x 8 rows of this sequence
    __shared__ float iv[3][32];         // [sh,pv,full] inverse norms, idx = input*8+row
    __shared__ float red[3];
    const int s = blockIdx.x;
    const int tid = threadIdx.x;

    int gid = s * 256 + tid;
    if (gid < 2080) ws[gid] = 0.0f;                 // arrival counters (L1 + L2)
    if (gid < 50176) ws[RS_T + gid] = 0.0f;         // rowsums + slots
    if (tid < 3) red[tid] = 0.0f;

    #pragma unroll
    for (int i = 0; i < 4; i++) {
        int e4 = tid + i * 256;
        int inp = e4 >> 8, row = (e4 >> 5) & 7, c4 = e4 & 31;
        float4 f = *(const float4*)(pick4(in0, in1, in2, in3, inp) + (size_t)(s * 8 + row) * 128 + c4 * 4);
        *(float4*)(&buf[inp][row][c4 * 4]) = f;
    }
    __syncthreads();

    // norms: thread = (row32 = tid>>3) x (seg = tid&7), 16 els each; segs 0..3 = sh half
    {
        int row32 = tid >> 3, seg = tid & 7;
        const float* rp_ = &buf[row32 >> 3][row32 & 7][seg * 16];
        float ss = 0.0f;
        #pragma unroll
        for (int k = 0; k < 4; k++) {
            float4 x = *(const float4*)(rp_ + k * 4);
            ss = fmaf(x.x, x.x, fmaf(x.y, x.y, fmaf(x.z, x.z, fmaf(x.w, x.w, ss))));
        }
        ss += __shfl_xor(ss, 1); ss += __shfl_xor(ss, 2);   // sum own half
        float cross = __shfl_xor(ss, 4);                    // other half
        if (seg == 0) {
            iv[0][row32] = 1.0f / fmaxf(sqrtf(ss), EPS_N);          // sh
            iv[2][row32] = 1.0f / fmaxf(sqrtf(ss + cross), EPS_N);  // full
        }
        if (seg == 4) iv[1][row32] = 1.0f / fmaxf(sqrtf(ss), EPS_N); // pv
    }
    __syncthreads();

    // convert: thread = input(t>>6) x row((t>>3)&7) x 16-col chunk ((t&7)*16)
    {
        int input = tid >> 6, row = (tid >> 3) & 7, cs = (tid & 7) * 16;
        float scF = iv[2][input * 8 + row];
        float scH = iv[cs < 64 ? 0 : 1][input * 8 + row];
        unsigned short* zf = (unsigned short*)((char*)ws + ZF_BYTE) + (size_t)input * 524288 + (size_t)(s * 8 + row) * 128 + cs;
        unsigned short* zh = (unsigned short*)((char*)ws + ZH_BYTE) + (size_t)input * 524288 + (size_t)(s * 8 + row) * 128 + cs;
        const float* bp = &buf[input][row][cs];
        #pragma unroll
        for (int k4 = 0; k4 < 4; k4++) {
            float4 x = *(const float4*)(bp + k4 * 4);
            ushort4 of, oh;
            of.x = f2bf(x.x * scF); of.y = f2bf(x.y * scF); of.z = f2bf(x.z * scF); of.w = f2bf(x.w * scF);
            oh.x = f2bf(x.x * scH); oh.y = f2bf(x.y * scH); oh.z = f2bf(x.z * scH); oh.w = f2bf(x.w * scH);
            *(ushort4*)(zf + k4 * 4) = of;
            *(ushort4*)(zh + k4 * 4) = oh;
        }
    }

    // small dots: ortho (tid<48), contrastive pos (48..79), temporal pos (80..135)
    float val = 0.0f;
    int cat = -1;
    if (tid < 48) {
        const int oa[6]  = {0, 2, 1, 3, 0, 1};
        const int oaf[6] = {0, 0, 0, 0, 64, 64};
        const int ob[6]  = {0, 2, 1, 3, 2, 3};
        int term = tid >> 3, row = tid & 7;
        const float* A = &buf[oa[term]][row][oaf[term]];
        const float* B = &buf[ob[term]][row][64];
        float d = 0.0f;
        #pragma unroll
        for (int k = 0; k < 16; k++) {
            float4 x = *(const float4*)(A + k * 4);
            float4 y = *(const float4*)(B + k * 4);
            d = fmaf(x.x, y.x, fmaf(x.y, y.y, fmaf(x.z, y.z, fmaf(x.w, y.w, d))));
        }
        float ia = iv[oaf[term] ? 1 : 0][oa[term] * 8 + row];
        float ib = iv[1][ob[term] * 8 + row];
        val = fmaxf(d * ia * ib, 0.0f);
        cat = 2;
    } else if (tid < 80) {
        const int ca[4] = {0, 1, 0, 2}, cb[4] = {2, 3, 1, 3}, coff[4] = {0, 0, 64, 64};
        int call = (tid - 48) >> 3, row = (tid - 48) & 7;
        const float* A = &buf[ca[call]][row][coff[call]];
        const float* B = &buf[cb[call]][row][coff[call]];
        float d = 0.0f;
        #pragma unroll
        for (int k = 0; k < 16; k++) {
            float4 x = *(const float4*)(A + k * 4);
            float4 y = *(const float4*)(B + k * 4);
            d = fmaf(x.x, y.x, fmaf(x.y, y.y, fmaf(x.z, y.z, fmaf(x.w, y.w, d))));
        }
        int ivb = coff[call] ? 1 : 0;
        val = d * iv[ivb][ca[call] * 8 + row] * iv[ivb][cb[call] * 8 + row];
        cat = 0;
    } else if (tid < 136) {
        int u = tid - 80;
        int inp = u / 14, v = u % 14, pp = v >> 1, half = v & 1;
        int ra = (pp == 0) ? 1 : (pp + 1);
        const float* A = &buf[inp][ra][half * 64];
        const float* B = &buf[inp][0][half * 64];
        float d = 0.0f;
        #pragma unroll
        for (int k = 0; k < 16; k++) {
            float4 x = *(const float4*)(A + k * 4);
            float4 y = *(const float4*)(B + k * 4);
            d = fmaf(x.x, y.x, fmaf(x.y, y.y, fmaf(x.z, y.z, fmaf(x.w, y.w, d))));
        }
        float wgt = (pp == 0) ? 2.0f : 1.0f;
        val = d * wgt * iv[2][inp * 8 + ra] * iv[2][inp * 8];
        cat = 1;
    }
    if (cat >= 0) atomicAdd(&red[cat], val);
    __syncthreads();
    if (tid == 0) atomicAdd(ws + SLOT + 32 * 24, red[0]);
    if (tid == 1) atomicAdd(ws + SLOT + 32 * 25, red[1]);
    if (tid == 2) atomicAdd(ws + SLOT + 32 * (16 + (s & 7)), red[2]);
}

// ---------- unified symmetric gram (global_load_lds staging, swizzled LDS) ----------
// blocks [0,2176) temporal (4 inputs x 544), [2176,3456) contrastive (32 x 40)
// LDS layout: buffer[128 rows][8 chunks of 16B]; slot (r,c) holds global chunk
// (r, c ^ (r&7)). Deposit is contiguous (lane x 16B); reads are 2-way = free.
__global__ __launch_bounds__(256) void k_gram(float* __restrict__ ws) {
    __shared__ short rowbuf[128 * 64];
    __shared__ short colbuf[128 * 64];
    const int tid = threadIdx.x;
    const int b = blockIdx.x;

    const short* baseR;
    const short* baseC;
    int rstride, nk;
    float* rsR;
    float* rsC;
    bool diag;

    if (b < 2176) {
        int input = b / 544, t = b % 544;
        int j = t >> 5, i = t & 31;
        if (j == 16 && i >= 16) return;          // folded duplicate
        int rt = i, ct = (i + j) & 31;
        diag = (j == 0);
        const short* zf = (const short*)((const char*)ws + ZF_BYTE) + (size_t)input * 524288;
        baseR = zf + rt * 16384;
        baseC = zf + ct * 16384;
        rstride = 128; nk = 2;
        rsR = ws + RS_T + input * 4096 + rt * 128;
        rsC = ws + RS_T + input * 4096 + ct * 128;
    } else {
        int c = b - 2176;
        int callp = c / 40, t = c % 40;
        int j = t >> 3, i = t & 7;
        if (j == 4 && i >= 4) return;
        int call = callp >> 3, p = callp & 7;
        int rt = i, ct = (i + j) & 7;
        diag = (j == 0);
        const int ca[4] = {0, 1, 0, 2}, cb[4] = {2, 3, 1, 3}, coff[4] = {0, 0, 64, 64};
        const short* zh = (const short*)((const char*)ws + ZH_BYTE);
        int rbase = rt * 128, cbase = ct * 128;
        baseR = zh + (size_t)(rbase < 512 ? ca[call] : cb[call]) * 524288
                   + (size_t)((rbase & 511) * 8 + p) * 128 + coff[call];
        baseC = zh + (size_t)(cbase < 512 ? ca[call] : cb[call]) * 524288
                   + (size_t)((cbase & 511) * 8 + p) * 128 + coff[call];
        rstride = 1024; nk = 1;
        rsR = ws + RS_C + (call * 8 + p) * 1024 + rbase;
        rsC = ws + RS_C + (call * 8 + p) * 1024 + cbase;
    }

    floatx4 acc[4][4];
    #pragma unroll
    for (int ri = 0; ri < 4; ri++)
        #pragma unroll
        for (int ci = 0; ci < 4; ci++) acc[ri][ci] = (floatx4){0.f, 0.f, 0.f, 0.f};

    const int w = tid >> 6, lane = tid & 63, quad = (tid >> 4) & 3, l15 = tid & 15;
    const int wrow = (w >> 1) * 64, wcol = (w & 1) * 64;
    const short* bbuf = diag ? rowbuf : colbuf;

    for (int st = 0; st < nk; st++) {
        if (st) __syncthreads();
        const int kbase = st * 64;
        #pragma unroll
        for (int i = 0; i < 4; i++) {
            int chunk = i * 256 + tid;
            int r = chunk >> 3, c = chunk & 7;
            int cs = (c ^ (r & 7)) << 3;                      // swizzled chunk, in shorts
            int wbase = (i * 256 + (tid & ~63)) << 3;         // wave-uniform LDS base (shorts)
            load_lds16(baseR + (size_t)r * rstride + kbase + cs, rowbuf + wbase);
            if (!diag)
                load_lds16(baseC + (size_t)r * rstride + kbase + cs, colbuf + wbase);
        }
        __syncthreads();   // s_waitcnt vmcnt(0) drains the DMA before reads
        #pragma unroll
        for (int ks = 0; ks < 2; ks++) {
            short8 a[4], bb[4];
            int cr = (ks << 2) + quad;                        // 16B chunk index 0..7
            #pragma unroll
            for (int i = 0; i < 4; i++) {
                int ra_ = wrow + i * 16 + l15;
                int rb_ = wcol + i * 16 + l15;
                a[i]  = *(const short8*)(rowbuf + ra_ * 64 + ((cr ^ (ra_ & 7)) << 3));
                bb[i] = *(const short8*)(bbuf   + rb_ * 64 + ((cr ^ (rb_ & 7)) << 3));
            }
            #pragma unroll
            for (int ri = 0; ri < 4; ri++)
                #pragma unroll
                for (int ci = 0; ci < 4; ci++)
                    acc[ri][ci] = __builtin_amdgcn_mfma_f32_16x16x32_bf16(a[ri], bb[ci], acc[ri][ci], 0, 0, 0);
        }
    }

    if (diag) {
        #pragma unroll
        for (int ri = 0; ri < 4; ri++) {
            #pragma unroll
            for (int reg = 0; reg < 4; reg++) {
                int rloc = wrow + ri * 16 + quad * 4 + reg;
                float rp = 0.f;
                #pragma unroll
                for (int ci = 0; ci < 4; ci++) {
                    int cloc = wcol + ci * 16 + l15;
                    float ex = __builtin_amdgcn_exp2f(fmaf(acc[ri][ci][reg], C1EXP, -C1EXP));
                    rp += (cloc != rloc) ? ex : 0.f;   // exact diag exclusion
                }
                rp += __shfl_xor(rp, 1); rp += __shfl_xor(rp, 2);
                rp += __shfl_xor(rp, 4); rp += __shfl_xor(rp, 8);
                if (l15 == 0) atomicAdd(rsR + rloc, rp);
            }
        }
    } else {
        float colp[4] = {0.f, 0.f, 0.f, 0.f};
        #pragma unroll
        for (int ri = 0; ri < 4; ri++) {
            #pragma unroll
            for (int reg = 0; reg < 4; reg++) {
                int rloc = wrow + ri * 16 + quad * 4 + reg;
                float rp = 0.f;
                #pragma unroll
                for (int ci = 0; ci < 4; ci++) {
                    float ex = __builtin_amdgcn_exp2f(fmaf(acc[ri][ci][reg], C1EXP, -C1EXP));
                    rp += ex;
                    colp[ci] += ex;
                }
                rp += __shfl_xor(rp, 1); rp += __shfl_xor(rp, 2);
                rp += __shfl_xor(rp, 4); rp += __shfl_xor(rp, 8);
                if (l15 == 0) atomicAdd(rsR + rloc, rp);
            }
        }
        #pragma unroll
        for (int ci = 0; ci < 4; ci++) {           // transpose contribution
            colp[ci] += __shfl_xor(colp[ci], 16);
            colp[ci] += __shfl_xor(colp[ci], 32);
            if (lane < 16) atomicAdd(rsC + wcol + ci * 16 + l15, colp[ci]);
        }
    }
}

// ---------- tail: grid-parallel logsum + arrival-gated final ----------
__global__ __launch_bounds__(256) void k_tail(float* __restrict__ ws, float* __restrict__ out) {
    __shared__ float tred[4];
    __shared__ int lastf;
    const int tid = threadIdx.x;
    const int b = blockIdx.x;
    const int idx = b * 256 + tid;       // blocks 0..63 temporal, 64..191 contrastive

    float l = __logf(ws[RS_T + idx]);
    #pragma unroll
    for (int m = 1; m < 64; m <<= 1) l += __shfl_xor(l, m);
    if ((tid & 63) == 0) tred[tid >> 6] = l;
    __syncthreads();
    if (tid == 0) {
        float bs = tred[0] + tred[1] + tred[2] + tred[3];
        int slot = (idx < 16384) ? (8 + (b & 7)) : (b & 7);
        atomicAdd(ws + SLOT + 32 * slot, bs);
    }
    __syncthreads();   // vmcnt(0): slot atomic completed before counter RMW
    if (tid == 0) {
        int last = 0;
        int o1 = __hip_atomic_fetch_add((int*)(ws + CTR_L1 + 32 * (b & 7)), 1,
                                        __ATOMIC_RELAXED, __HIP_MEMORY_SCOPE_AGENT);
        if (o1 == 23) {
            int o2 = __hip_atomic_fetch_add((int*)(ws + CTR_L2), 1,
                                            __ATOMIC_RELAXED, __HIP_MEMORY_SCOPE_AGENT);
            last = (o2 == 7);
        }
        lastf = last;
    }
    __syncthreads();
    if (!lastf) return;

    if (tid < 64) {                      // lane-parallel final combine
        float v2 = 0.0f;
        if (tid < 26) {
            float x = __hip_atomic_load(ws + SLOT + 32 * tid, __ATOMIC_RELAXED, __HIP_MEMORY_SCOPE_AGENT);
            float wgt;
            if (tid < 8)       wgt = 1.0f / 8192.0f;             // c-log
            else if (tid < 24) wgt = 1.0f / 4096.0f;             // t-log + ortho
            else if (tid == 24) wgt = -2.0f * INV_T / 8192.0f;   // posC
            else                wgt = -INV_T / 4096.0f;          // posT
            v2 = x * wgt;
        }
        #pragma unroll
        for (int m = 1; m < 64; m <<= 1) v2 += __shfl_xor(v2, m);
        if (tid == 0) out[0] = v2 + 8.0f * INV_T;   // 32768*INV_T/8192 + 16384*INV_T/4096
    }
}

extern "C" void kernel_launch(void* const* d_in, const int* in_sizes, int n_in,
                              void* d_out, int out_size, void* d_ws, size_t ws_size,
                              hipStream_t stream) {
    (void)in_sizes; (void)n_in; (void)out_size; (void)ws_size;
    const float* in0 = (const float*)d_in[0];
    const float* in1 = (const float*)d_in[1];
    const float* in2 = (const float*)d_in[2];
    const float* in3 = (const float*)d_in[3];
    float* ws = (float*)d_ws;
    float* out = (float*)d_out;

    hipLaunchKernelGGL(k_prep, dim3(512), dim3(256), 0, stream, in0, in1, in2, in3, ws);
    hipLaunchKernelGGL(k_gram, dim3(3456), dim3(256), 0, stream, ws);
    hipLaunchKernelGGL(k_tail, dim3(NBLK_TAIL), dim3(256), 0, stream, ws, out);
}